// Round 2
// baseline (21.295 us; speedup 1.0000x reference)
//
#include <hip/hip_runtime.h>

// MarginRankingLoss over all B*B pairs.
// loss[m,n] = max(0, BIAS - 0.5*(w_m+w_n)*|p_m-p_n|)  (exact per-pair rewrite:
// the gt tie-break only affects r when diff==0, where r*diff==0 anyway).
// Symmetry: loss[m,n] == loss[n,m]; diagonal loss[m,m] == BIAS.
//   total = 2 * sum_{n>m} loss[m,n] + B*BIAS
// -> compute only the upper triangle (halves the VALU work).

#define BIAS_F 0.1f

constexpr int TPB = 256;       // threads per block
constexpr int NPT = 2;         // n-values per thread (registers)
constexpr int TN  = TPB * NPT; // 512 n per tile
constexpr int TM  = 32;        // m per tile

__global__ __launch_bounds__(TPB) void pair_loss_kernel(
    const float* __restrict__ pred,
    const float* __restrict__ weight,
    float* __restrict__ partial,
    int B)
{
    const int n0 = blockIdx.x * TN;
    const int m0 = blockIdx.y * TM;
    const int bid = blockIdx.y * gridDim.x + blockIdx.x;
    const int t = threadIdx.x;

    // Entire tile at-or-below diagonal (no n > m pairs): contribute 0.
    if (n0 + TN - 1 <= m0) {
        if (t == 0) partial[bid] = 0.0f;
        return;
    }

    // Per-thread n-data in registers.
    float pn[NPT], wnh[NPT];
    int nidx[NPT]; // n index, or -1 if out of range (fails n>m test)
    #pragma unroll
    for (int j = 0; j < NPT; ++j) {
        int n = n0 + j * TPB + t;
        bool ok = (n < B);
        int nc = ok ? n : 0;
        pn[j]   = pred[nc];
        wnh[j]  = weight[nc] * 0.5f;
        nidx[j] = ok ? n : -1;
    }

    float acc[NPT];
    #pragma unroll
    for (int j = 0; j < NPT; ++j) acc[j] = 0.0f;

    const bool clean = (n0 >= m0 + TM) && (n0 + TN <= B) && (m0 + TM <= B);

    if (clean) {
        // All pairs in tile satisfy n > m and are in range: no masking.
        #pragma unroll 4
        for (int i = 0; i < TM; ++i) {
            const int m = m0 + i;
            const float pm  = pred[m];          // uniform -> scalar load
            const float wmh = weight[m] * 0.5f;
            #pragma unroll
            for (int j = 0; j < NPT; ++j) {
                float d  = pm - pn[j];
                float w  = wmh + wnh[j];
                float th = fmaf(-w, fabsf(d), BIAS_F); // BIAS - w*|d|
                acc[j] += fmaxf(th, 0.0f);
            }
        }
    } else {
        // Diagonal-crossing or edge tile: mask per pair.
        const int m_end = (m0 + TM <= B) ? TM : (B - m0);
        for (int i = 0; i < m_end; ++i) {
            const int m = m0 + i;
            const float pm  = pred[m];
            const float wmh = weight[m] * 0.5f;
            #pragma unroll
            for (int j = 0; j < NPT; ++j) {
                float d  = pm - pn[j];
                float w  = wmh + wnh[j];
                float th = fmaf(-w, fabsf(d), BIAS_F);
                float h  = fmaxf(th, 0.0f);
                acc[j] += (nidx[j] > m) ? h : 0.0f;
            }
        }
    }

    float s = acc[0];
    #pragma unroll
    for (int j = 1; j < NPT; ++j) s += acc[j];

    // wave (64-lane) reduction
    #pragma unroll
    for (int off = 32; off > 0; off >>= 1)
        s += __shfl_down(s, off, 64);

    __shared__ float lds[TPB / 64];
    const int lane = t & 63, wid = t >> 6;
    if (lane == 0) lds[wid] = s;
    __syncthreads();
    if (t == 0) {
        float bs = 0.0f;
        #pragma unroll
        for (int w = 0; w < TPB / 64; ++w) bs += lds[w];
        partial[bid] = bs;
    }
}

__global__ __launch_bounds__(256) void reduce_kernel(
    const float* __restrict__ partial, int n, float* __restrict__ out, int B)
{
    double s = 0.0;
    for (int i = threadIdx.x; i < n; i += 256) s += (double)partial[i];
    #pragma unroll
    for (int off = 32; off > 0; off >>= 1)
        s += __shfl_down(s, off, 64);
    __shared__ double lds[4];
    const int lane = threadIdx.x & 63, wid = threadIdx.x >> 6;
    if (lane == 0) lds[wid] = s;
    __syncthreads();
    if (threadIdx.x == 0) {
        double tot = lds[0] + lds[1] + lds[2] + lds[3];
        // total over full matrix = 2*upper + B*BIAS
        double full = 2.0 * tot + (double)B * (double)BIAS_F;
        out[0] = (float)(full / ((double)B * (double)B));
    }
}

extern "C" void kernel_launch(void* const* d_in, const int* in_sizes, int n_in,
                              void* d_out, int out_size, void* d_ws, size_t ws_size,
                              hipStream_t stream) {
    const float* pred   = (const float*)d_in[0];
    // d_in[1] = correct_output — mathematically irrelevant (see header comment)
    const float* weight = (const float*)d_in[2];
    float* out = (float*)d_out;
    const int B = in_sizes[0];

    const int tilesN = (B + TN - 1) / TN;  // 16 at B=8192
    const int tilesM = (B + TM - 1) / TM;  // 256 at B=8192
    float* partial = (float*)d_ws;         // tilesN*tilesM floats (16 KB)

    dim3 grid(tilesN, tilesM);
    pair_loss_kernel<<<grid, TPB, 0, stream>>>(pred, weight, partial, B);
    reduce_kernel<<<1, 256, 0, stream>>>(partial, tilesN * tilesM, out, B);
}